// Round 9
// baseline (347.262 us; speedup 1.0000x reference)
//
#include <hip/hip_runtime.h>
#include <hip/hip_bf16.h>

// Causal GQA flash-attention prefill, fixture: B=8, S=1024, H=32, KVH=8,
// D=128, scale=1/sqrt(128). Identity paging -> read q,k,v directly.
//
// v8: two kernels.
//  (1) preconv: k,v fp32 -> d_ws as PRE-SWIZZLED bf16 LDS tile images
//      (K [key][d] with byte^=((key&15)<<4); V^T [d][key] with
//      byte^=((d&7)<<4); V transposed via LDS bounce). 1024 wg = (b,kvh,t).
//  (2) attn_fwd: att[2] deferred-PV pipeline. Staging = 4 x
//      global_load_lds(16B)/thread/tile (linear copy of the image; zero
//      staging regs/VALU). Defers only the PACKED bf16 P (16 regs, not 32):
//      iter i: STAGE(i+1) | QK(i) | PV(i-1) | mask | maxmerge | exp+pack.
//      Rescale-after-PV keeps online softmax exact. 3 LDS buffers (96 KB),
//      one __syncthreads/tile (loads issued at iter top, drained at bottom).
//      Band pairing: uniform 17 tiles/block, 512 blocks.
// Fallback: proven v5 kernel if ws_size < 32 MB.

namespace {

constexpr int Bc = 8, Sc = 1024, Hc = 32, KVHc = 8, Dc = 128;
constexpr float SCALEc = 0.08838834764831845f;
constexpr int KVBLK = 64;
constexpr int KD = KVHc * Dc;      // 1024
constexpr int HD = Hc * Dc;        // 4096
constexpr int NT = 17;             // tiles per block (uniform via band pairing)
constexpr int IMG = KVBLK * Dc;    // 8192 elements = 16 KB per tile image

typedef __attribute__((ext_vector_type(8))) short bf16x8;
typedef __attribute__((ext_vector_type(16))) float f32x16;

__device__ __forceinline__ unsigned short f2bf(float f) {
  union { __hip_bfloat16 h; unsigned short u; } c;
  c.h = __float2bfloat16(f);
  return c.u;
}
__device__ __forceinline__ unsigned pack2(float a, float b) {
  return (unsigned)f2bf(a) | ((unsigned)f2bf(b) << 16);
}
__device__ __forceinline__ void pl32swap(unsigned& a, unsigned& b) {
  asm volatile("v_permlane32_swap_b32 %0, %1" : "+v"(a), "+v"(b));
}
__device__ __forceinline__ void gload_lds16(const void* g, void* l) {
  __builtin_amdgcn_global_load_lds(
      (const __attribute__((address_space(1))) void*)g,
      (__attribute__((address_space(3))) void*)l, 16, 0, 0);
}

// ---------------- pre-pass: build swizzled bf16 tile images ----------------
__global__ __launch_bounds__(256) void preconv(
    const float* __restrict__ kg, const float* __restrict__ vg,
    unsigned short* __restrict__ wsK, unsigned short* __restrict__ wsV) {
  const int img = blockIdx.x;            // (b*8+kvh)*16 + t
  const int t = img & 15;
  const int kvh = (img >> 4) & 7;
  const int b = img >> 7;
  const int tid = threadIdx.x;
  const size_t row0 = (size_t)(b * Sc + t * 64);

  // K image: LDS[row*256 + y] = bf16(K[row][(y ^ ((row&15)<<4))/2])
  uint4* outK = (uint4*)(wsK + (size_t)img * IMG);
  const float* kp = kg + row0 * KD + kvh * Dc;
#pragma unroll
  for (int cc = 0; cc < 4; ++cc) {
    const int c = cc * 256 + tid;        // 16B chunk id, 0..1023
    const int r = c >> 4, yc = c & 15;
    const int d0 = ((yc * 16) ^ ((r & 15) << 4)) >> 1;
    const float* s = kp + (size_t)r * KD + d0;
    float4 x = *(const float4*)(s);
    float4 y = *(const float4*)(s + 4);
    uint4 o;
    o.x = pack2(x.x, x.y); o.y = pack2(x.z, x.w);
    o.z = pack2(y.x, y.y); o.w = pack2(y.z, y.w);
    outK[c] = o;
  }

  // V^T image via LDS bounce: LDS[d*128 + y] = bf16(V[(y^((d&7)<<4))/2][d])
  __shared__ unsigned short tmp[64 * 128];   // [key][d] bf16, linear
  const float* vp = vg + row0 * KD + kvh * Dc;
#pragma unroll
  for (int cc = 0; cc < 8; ++cc) {
    const int c2 = cc * 256 + tid;       // 0..2047, 4 floats each
    const int key = c2 >> 5, dc = (c2 & 31) * 4;
    float4 x = *(const float4*)(vp + (size_t)key * KD + dc);
    uint2 o;
    o.x = pack2(x.x, x.y); o.y = pack2(x.z, x.w);
    *(uint2*)(tmp + key * 128 + dc) = o;
  }
  __syncthreads();
  uint4* outV = (uint4*)(wsV + (size_t)img * IMG);
#pragma unroll
  for (int cc = 0; cc < 4; ++cc) {
    const int c = cc * 256 + tid;        // 0..1023
    const int d = c >> 3, yc = c & 7;
    const int k0 = ((yc * 16) ^ ((d & 7) << 4)) >> 1;
    uint4 o;
    o.x = tmp[(k0 + 0) * 128 + d] | ((unsigned)tmp[(k0 + 1) * 128 + d] << 16);
    o.y = tmp[(k0 + 2) * 128 + d] | ((unsigned)tmp[(k0 + 3) * 128 + d] << 16);
    o.z = tmp[(k0 + 4) * 128 + d] | ((unsigned)tmp[(k0 + 5) * 128 + d] << 16);
    o.w = tmp[(k0 + 6) * 128 + d] | ((unsigned)tmp[(k0 + 7) * 128 + d] << 16);
    outV[c] = o;
  }
}

// ---------------- shared MFMA helpers ----------------
// QK^T subtile ST (32 keys): S^T fragment; lane holds q=lane&31,
// k_local = (reg&3)+8*(reg>>2)+4*hi (+ST*32).
template <int ST>
__device__ __forceinline__ f32x16 qk_sub(const unsigned short* KB,
                                         const bf16x8* qf, int q32, int hi) {
  f32x16 a;
#pragma unroll
  for (int i = 0; i < 16; ++i) a[i] = 0.f;
  const int key = ST * 32 + q32;
  const char* kb = (const char*)KB + key * 256;
  const int sw = (key & 15) << 4;
#pragma unroll
  for (int ks = 0; ks < 8; ++ks) {
    bf16x8 kf = *(const bf16x8*)(kb + ((ks * 32 + hi * 16) ^ sw));
    a = __builtin_amdgcn_mfma_f32_32x32x16_bf16(kf, qf[ks], a, 0, 0, 0);
  }
  return a;
}

// pack exp'd P (f32x16) -> 8 A-frag words (permlane-swapped, both halves).
__device__ __forceinline__ void pack_frags(const f32x16& p, unsigned* pp) {
  unsigned cp[8];
#pragma unroll
  for (int j = 0; j < 8; ++j) cp[j] = pack2(p[2 * j], p[2 * j + 1]);
  pl32swap(cp[0], cp[2]);
  pl32swap(cp[1], cp[3]);
  pl32swap(cp[4], cp[6]);
  pl32swap(cp[5], cp[7]);
#pragma unroll
  for (int j = 0; j < 8; ++j) pp[j] = cp[j];
}

// PV from packed frags: acc[dt] += V^T[d][k] * P^T[k][q].
template <int ST>
__device__ __forceinline__ void pv_packed(const unsigned short* VB,
                                          const unsigned* pp, f32x16* acc,
                                          int q32, int hi) {
  union { bf16x8 v; unsigned u[4]; } f0, f1;
  f0.u[0] = pp[0]; f0.u[1] = pp[1]; f0.u[2] = pp[2]; f0.u[3] = pp[3];
  f1.u[0] = pp[4]; f1.u[1] = pp[5]; f1.u[2] = pp[6]; f1.u[3] = pp[7];
#pragma unroll
  for (int ks2 = 0; ks2 < 2; ++ks2) {
    const bf16x8 pa = ks2 ? f1.v : f0.v;
#pragma unroll
    for (int dt = 0; dt < 4; ++dt) {
      const int d = dt * 32 + q32;
      const bf16x8 vf = *(const bf16x8*)(
          (const char*)VB + d * 128 +
          ((ST * 64 + ks2 * 32 + hi * 16) ^ ((d & 7) << 4)));
      acc[dt] = __builtin_amdgcn_mfma_f32_32x32x16_bf16(vf, pa, acc[dt], 0, 0, 0);
    }
  }
}

// legacy combined pack+PV (fallback kernel)
template <int ST>
__device__ __forceinline__ void pv_sub_fb(const unsigned short* VB,
                                          const f32x16& p, f32x16* acc,
                                          int q32, int hi) {
  unsigned pp[8];
  pack_frags(p, pp);
  pv_packed<ST>(VB, pp, acc, q32, hi);
}

// ---------------- main kernel (v8) ----------------
__global__ __launch_bounds__(512, 1) void attn_fwd(
    const float* __restrict__ qg,
    const unsigned short* __restrict__ wsK,
    const unsigned short* __restrict__ wsV,
    float* __restrict__ out) {
  const int bid = blockIdx.x;
  const int j   = bid >> 6;            // pair index 0..7
  const int kvh = bid & 7;
  const int b   = (bid >> 3) & 7;
  const int nA  = 16 - j;              // tiles in band A (= band 15-j)
  const int bh  = b * 8 + kvh;

  const int tid = threadIdx.x;
  const int w = tid >> 6, l = tid & 63;
  const int q32 = l & 31, hi = l >> 5;
  const int h = kvh * 4 + (w >> 1);
  const int stdiag = w & 1;

  int qbase = (15 - j) * 64 + (w & 1) * 32;   // band A first

  __shared__ unsigned short Kl[3][IMG];
  __shared__ unsigned short Vt[3][IMG];

  bf16x8 qf[8];
  auto LOADQ = [&](int qb_) {
    const float* qp = qg + (size_t)(b * Sc + qb_ + q32) * HD + h * Dc;
#pragma unroll
    for (int ks = 0; ks < 8; ++ks) {
      const int d0 = ks * 16 + hi * 8;
      float4 x = *(const float4*)(qp + d0);
      float4 y = *(const float4*)(qp + d0 + 4);
      bf16x8 t;
      t[0] = (short)f2bf(x.x * SCALEc); t[1] = (short)f2bf(x.y * SCALEc);
      t[2] = (short)f2bf(x.z * SCALEc); t[3] = (short)f2bf(x.w * SCALEc);
      t[4] = (short)f2bf(y.x * SCALEc); t[5] = (short)f2bf(y.y * SCALEc);
      t[6] = (short)f2bf(y.z * SCALEc); t[7] = (short)f2bf(y.w * SCALEc);
      qf[ks] = t;
    }
  };
  LOADQ(qbase);

  f32x16 acc[4];
#pragma unroll
  for (int dt = 0; dt < 4; ++dt)
#pragma unroll
    for (int i = 0; i < 16; ++i) acc[dt][i] = 0.f;
  float m = -1e30f, lsum = 0.f;

  auto WRITEO = [&](int qb_) {
    const float rinv = 1.0f / lsum;
    float* ob = out + (size_t)(b * Sc + qb_ + q32) * HD + h * Dc;
#pragma unroll
    for (int dt = 0; dt < 4; ++dt)
#pragma unroll
      for (int g = 0; g < 4; ++g) {
        float4 o;
        o.x = acc[dt][g * 4 + 0] * rinv;
        o.y = acc[dt][g * 4 + 1] * rinv;
        o.z = acc[dt][g * 4 + 2] * rinv;
        o.w = acc[dt][g * 4 + 3] * rinv;
        *(float4*)(ob + dt * 32 + g * 8 + hi * 4) = o;
      }
  };

  // staging: linear copy of pre-swizzled images, 4 x 1KB chunks per wave.
  auto STAGE = [&](int T, int cb) {
    const char* sK = (const char*)(wsK + ((size_t)bh * 16 + T) * IMG);
    const char* sV = (const char*)(wsV + ((size_t)bh * 16 + T) * IMG);
    char* dK = (char*)&Kl[cb][0];
    char* dV = (char*)&Vt[cb][0];
    const int off = w * 2048;            // wave-uniform
    gload_lds16(sK + off + l * 16, dK + off);
    gload_lds16(sK + off + 1024 + l * 16, dK + off + 1024);
    gload_lds16(sV + off + l * 16, dV + off);
    gload_lds16(sV + off + 1024 + l * 16, dV + off + 1024);
  };
  auto KT = [&](int i) { return i < nA ? i : i - nA; };

  // pipeline state: packed P of previous tile
  unsigned pp0[8], pp1[8];
  bool has1p = true;

  auto MASK = [&](int i, f32x16& p0, f32x16& p1) {
    const int kt = KT(i);
    const int kmb = kt * KVBLK + stdiag * 32 + 4 * hi - qbase - q32;
    if (stdiag == 0) {
#pragma unroll
      for (int z = 0; z < 16; ++z) {
        const int kl = (z & 3) + 8 * (z >> 2);
        if (kmb + kl > 0) p0[z] = -1e30f;
      }
    } else {
#pragma unroll
      for (int z = 0; z < 16; ++z) {
        const int kl = (z & 3) + 8 * (z >> 2);
        if (kmb + kl > 0) p1[z] = -1e30f;
      }
    }
  };
  auto MAXMERGE = [&](const f32x16& p0, const f32x16& p1, bool has1) {
    float pm = p0[0];
#pragma unroll
    for (int z = 1; z < 16; ++z) pm = fmaxf(pm, p0[z]);
    if (has1) {
#pragma unroll
      for (int z = 0; z < 16; ++z) pm = fmaxf(pm, p1[z]);
    }
    pm = fmaxf(pm, __shfl_xor(pm, 32));
    if (__any(pm > m + 8.0f)) {        // defer-max (T13)
      const float mn = fmaxf(m, pm);
      const float alpha = __expf(m - mn);
      m = mn;
      lsum *= alpha;
#pragma unroll
      for (int dt = 0; dt < 4; ++dt) acc[dt] *= alpha;
    }
  };

  // ---- prologue ----
  STAGE(0, 0);
  __syncthreads();

  {  // iter 0: QK only, pack (never last: nA >= 9)
    STAGE(KT(1), 1);
    f32x16 p0, p1;
    __builtin_amdgcn_s_setprio(1);
    p0 = qk_sub<0>(Kl[0], qf, q32, hi);
    p1 = qk_sub<1>(Kl[0], qf, q32, hi);
    __builtin_amdgcn_s_setprio(0);
    MAXMERGE(p0, p1, true);
    float se = 0.f;
#pragma unroll
    for (int z = 0; z < 16; ++z) { p0[z] = __expf(p0[z] - m); se += p0[z]; }
#pragma unroll
    for (int z = 0; z < 16; ++z) { p1[z] = __expf(p1[z] - m); se += p1[z]; }
    se += __shfl_xor(se, 32);
    lsum += se;
    pack_frags(p0, pp0);
    pack_frags(p1, pp1);
    has1p = true;
    __syncthreads();
  }

  for (int i = 1; i < NT; ++i) {
    if (i + 1 < NT) STAGE(KT(i + 1), (i + 1) % 3);

    const bool sw = (i == nA);
    if (sw) LOADQ(j * 64 + (w & 1) * 32);   // qf for band B (used by QK(i))

    const bool last = (i == nA - 1) || (i == NT - 1);
    const bool has1 = !(last && stdiag == 0);
    f32x16 p0, p1;
    __builtin_amdgcn_s_setprio(1);
    p0 = qk_sub<0>(Kl[i % 3], qf, q32, hi);
    if (has1) p1 = qk_sub<1>(Kl[i % 3], qf, q32, hi);
    // deferred PV(i-1): adds to acc in current m-scale (maxmerge runs after)
    pv_packed<0>(Vt[(i - 1) % 3], pp0, acc, q32, hi);
    if (has1p) pv_packed<1>(Vt[(i - 1) % 3], pp1, acc, q32, hi);
    __builtin_amdgcn_s_setprio(0);

    if (sw) {                 // band A fully accumulated -> flush, reset
      WRITEO(qbase);
      qbase = j * 64 + (w & 1) * 32;
#pragma unroll
      for (int dt = 0; dt < 4; ++dt)
#pragma unroll
        for (int z = 0; z < 16; ++z) acc[dt][z] = 0.f;
      m = -1e30f;
      lsum = 0.f;
    }

    if (last) MASK(i, p0, p1);
    MAXMERGE(p0, p1, has1);

    float se = 0.f;
#pragma unroll
    for (int z = 0; z < 16; ++z) { p0[z] = __expf(p0[z] - m); se += p0[z]; }
    if (has1) {
#pragma unroll
      for (int z = 0; z < 16; ++z) { p1[z] = __expf(p1[z] - m); se += p1[z]; }
    }
    se += __shfl_xor(se, 32);
    lsum += se;
    pack_frags(p0, pp0);
    if (has1) pack_frags(p1, pp1);
    has1p = has1;
    __syncthreads();
  }

  // ---- drain: PV of the last tile, write band B ----
  __builtin_amdgcn_s_setprio(1);
  pv_packed<0>(Vt[(NT - 1) % 3], pp0, acc, q32, hi);
  if (has1p) pv_packed<1>(Vt[(NT - 1) % 3], pp1, acc, q32, hi);
  __builtin_amdgcn_s_setprio(0);
  WRITEO(qbase);
}

// ---------------- fallback: proven v5 kernel ----------------
__global__ __launch_bounds__(512, 2) void attn_fwd_fb(
    const float* __restrict__ qg, const float* __restrict__ kg,
    const float* __restrict__ vg, float* __restrict__ out) {
  const int bid = blockIdx.x;
  const int j   = bid >> 6;
  const int kvh = bid & 7;
  const int b   = (bid >> 3) & 7;
  const int nA  = 16 - j;

  const int tid = threadIdx.x;
  const int w = tid >> 6, l = tid & 63;
  const int q32 = l & 31, hi = l >> 5;
  const int h = kvh * 4 + (w >> 1);
  const int stdiag = w & 1;

  int qbase = (15 - j) * 64 + (w & 1) * 32;

  __shared__ unsigned short Kl[2][KVBLK * Dc];
  __shared__ unsigned short Vt[2][Dc * KVBLK];

  bf16x8 qf[8];
  auto LOADQ = [&](int qb_) {
    const float* qp = qg + (size_t)(b * Sc + qb_ + q32) * HD + h * Dc;
#pragma unroll
    for (int ks = 0; ks < 8; ++ks) {
      const int d0 = ks * 16 + hi * 8;
      float4 x = *(const float4*)(qp + d0);
      float4 y = *(const float4*)(qp + d0 + 4);
      bf16x8 t;
      t[0] = (short)f2bf(x.x * SCALEc); t[1] = (short)f2bf(x.y * SCALEc);
      t[2] = (short)f2bf(x.z * SCALEc); t[3] = (short)f2bf(x.w * SCALEc);
      t[4] = (short)f2bf(y.x * SCALEc); t[5] = (short)f2bf(y.y * SCALEc);
      t[6] = (short)f2bf(y.z * SCALEc); t[7] = (short)f2bf(y.w * SCALEc);
      qf[ks] = t;
    }
  };
  LOADQ(qbase);

  f32x16 acc[4];
#pragma unroll
  for (int dt = 0; dt < 4; ++dt)
#pragma unroll
    for (int i = 0; i < 16; ++i) acc[dt][i] = 0.f;
  float m = -1e30f, lsum = 0.f;

  auto WRITEO = [&](int qb_) {
    const float rinv = 1.0f / lsum;
    float* ob = out + (size_t)(b * Sc + qb_ + q32) * HD + h * Dc;
#pragma unroll
    for (int dt = 0; dt < 4; ++dt)
#pragma unroll
      for (int g = 0; g < 4; ++g) {
        float4 o;
        o.x = acc[dt][g * 4 + 0] * rinv;
        o.y = acc[dt][g * 4 + 1] * rinv;
        o.z = acc[dt][g * 4 + 2] * rinv;
        o.w = acc[dt][g * 4 + 3] * rinv;
        *(float4*)(ob + dt * 32 + g * 8 + hi * 4) = o;
      }
  };

  const float* kb0 = kg + (size_t)(b * Sc) * KD + kvh * Dc;
  const float* vb0 = vg + (size_t)(b * Sc) * KD + kvh * Dc;
  const int krow = tid >> 3, kd0 = (tid & 7) * 16;
  const int vd = tid & 127, vk0 = (tid >> 7) * 16;
  float4 kreg[4];
  float vreg[16];

  auto LOAD = [&](int T) {
    const float* kp = kb0 + ((size_t)T * KVBLK + krow) * KD + kd0;
    kreg[0] = *(const float4*)(kp);
    kreg[1] = *(const float4*)(kp + 4);
    kreg[2] = *(const float4*)(kp + 8);
    kreg[3] = *(const float4*)(kp + 12);
    const float* vp = vb0 + ((size_t)T * KVBLK + vk0) * KD + vd;
#pragma unroll
    for (int jj = 0; jj < 16; ++jj) vreg[jj] = vp[(size_t)jj * KD];
  };
  auto STORE = [&](int cb) {
    unsigned short* KB = Kl[cb];
    unsigned short* VB = Vt[cb];
    uint4 A, Bq;
    A.x = pack2(kreg[0].x, kreg[0].y); A.y = pack2(kreg[0].z, kreg[0].w);
    A.z = pack2(kreg[1].x, kreg[1].y); A.w = pack2(kreg[1].z, kreg[1].w);
    Bq.x = pack2(kreg[2].x, kreg[2].y); Bq.y = pack2(kreg[2].z, kreg[2].w);
    Bq.z = pack2(kreg[3].x, kreg[3].y); Bq.w = pack2(kreg[3].z, kreg[3].w);
    const int kbase = krow * 256, ksw = (krow & 15) << 4;
    *(uint4*)((char*)KB + kbase + ((kd0 * 2) ^ ksw)) = A;
    *(uint4*)((char*)KB + kbase + ((kd0 * 2 + 16) ^ ksw)) = Bq;
    uint4 C0, C1;
    C0.x = pack2(vreg[0], vreg[1]);   C0.y = pack2(vreg[2], vreg[3]);
    C0.z = pack2(vreg[4], vreg[5]);   C0.w = pack2(vreg[6], vreg[7]);
    C1.x = pack2(vreg[8], vreg[9]);   C1.y = pack2(vreg[10], vreg[11]);
    C1.z = pack2(vreg[12], vreg[13]); C1.w = pack2(vreg[14], vreg[15]);
    const int vbase = vd * 128, vsw = (vd & 7) << 4;
    *(uint4*)((char*)VB + vbase + ((vk0 * 2) ^ vsw)) = C0;
    *(uint4*)((char*)VB + vbase + ((vk0 * 2 + 16) ^ vsw)) = C1;
  };
  auto KT = [&](int i) { return i < nA ? i : i - nA; };

  LOAD(0);
  STORE(0);
  LOAD(KT(1));
  __syncthreads();

  for (int i = 0; i < NT; ++i) {
    const int cb = i & 1;
    if (i + 1 < NT) {
      STORE(cb ^ 1);
      if (i + 2 < NT) LOAD(KT(i + 2));
    }
    if (i == nA) {
      WRITEO(qbase);
      qbase = j * 64 + (w & 1) * 32;
      LOADQ(qbase);
#pragma unroll
      for (int dt = 0; dt < 4; ++dt)
#pragma unroll
        for (int z = 0; z < 16; ++z) acc[dt][z] = 0.f;
      m = -1e30f;
      lsum = 0.f;
    }
    const int kt = KT(i);
    const unsigned short* KB = Kl[cb];
    const unsigned short* VB = Vt[cb];
    const bool last = (i == nA - 1) || (i == NT - 1);
    const bool has1 = !(last && stdiag == 0);

    f32x16 s[2];
    __builtin_amdgcn_s_setprio(1);
    s[0] = qk_sub<0>(KB, qf, q32, hi);
    if (has1) {
      s[1] = qk_sub<1>(KB, qf, q32, hi);
    } else {
#pragma unroll
      for (int z = 0; z < 16; ++z) s[1][z] = -1e30f;
    }
    __builtin_amdgcn_s_setprio(0);

    if (last) {
      const int kmb = kt * KVBLK + stdiag * 32 + 4 * hi - qbase - q32;
      if (stdiag == 0) {
#pragma unroll
        for (int z = 0; z < 16; ++z) {
          const int kl = (z & 3) + 8 * (z >> 2);
          if (kmb + kl > 0) s[0][z] = -1e30f;
        }
      } else {
#pragma unroll
        for (int z = 0; z < 16; ++z) {
          const int kl = (z & 3) + 8 * (z >> 2);
          if (kmb + kl > 0) s[1][z] = -1e30f;
        }
      }
    }

    float pm = fmaxf(s[0][0], s[1][0]);
#pragma unroll
    for (int z = 1; z < 16; ++z) pm = fmaxf(pm, fmaxf(s[0][z], s[1][z]));
    pm = fmaxf(pm, __shfl_xor(pm, 32));
    if (__any(pm > m + 8.0f)) {
      const float mn = fmaxf(m, pm);
      const float alpha = __expf(m - mn);
      m = mn;
      lsum *= alpha;
#pragma unroll
      for (int dt = 0; dt < 4; ++dt) acc[dt] *= alpha;
    }
    float se = 0.f;
#pragma unroll
    for (int z = 0; z < 16; ++z) { s[0][z] = __expf(s[0][z] - m); se += s[0][z]; }
    if (has1) {
#pragma unroll
      for (int z = 0; z < 16; ++z) { s[1][z] = __expf(s[1][z] - m); se += s[1][z]; }
    }
    se += __shfl_xor(se, 32);
    lsum += se;

    __builtin_amdgcn_s_setprio(1);
    pv_sub_fb<0>(VB, s[0], acc, q32, hi);
    if (has1) pv_sub_fb<1>(VB, s[1], acc, q32, hi);
    __builtin_amdgcn_s_setprio(0);

    __syncthreads();
  }

  WRITEO(qbase);
}

}  // namespace

extern "C" void kernel_launch(void* const* d_in, const int* in_sizes, int n_in,
                              void* d_out, int out_size, void* d_ws, size_t ws_size,
                              hipStream_t stream) {
  const float* q = (const float*)d_in[0];
  const float* k = (const float*)d_in[1];
  const float* v = (const float*)d_in[2];
  float* out = (float*)d_out;
  const size_t need = (size_t)2 * 1024 * IMG * sizeof(unsigned short);  // 32 MB
  if (ws_size >= need) {
    unsigned short* wsK = (unsigned short*)d_ws;
    unsigned short* wsV = wsK + (size_t)1024 * IMG;
    preconv<<<dim3(1024), dim3(256), 0, stream>>>(k, v, wsK, wsV);
    attn_fwd<<<dim3(512), dim3(512), 0, stream>>>(q, wsK, wsV, out);
  } else {
    attn_fwd_fb<<<dim3(512), dim3(512), 0, stream>>>(q, k, v, out);
  }
}

// Round 10
// 162.478 us; speedup vs baseline: 2.1373x; 2.1373x over previous
//
#include <hip/hip_runtime.h>
#include <hip/hip_bf16.h>

// Causal GQA flash-attention prefill, fixture: B=8, S=1024, H=32, KVH=8,
// D=128, scale=1/sqrt(128). Identity paging -> read q,k,v directly.
//
// v9 = v5 structure (PROVEN 155us: 2 LDS buffers 64KB -> 2 blocks/CU,
// reg-staged async-split staging, immediate PV, shfl_xor(32) reductions,
// defer-max, band pairing, setprio) with:
//  - preconv pre-pass (v8-proven): k,v fp32 -> d_ws as PRE-SWIZZLED bf16
//    LDS tile images. Main-kernel staging becomes a pure 32B/thread linear
//    copy per array (2 uint4 loads + 2 ds_writes) -- deletes ~80 convert
//    VALU ops/thread/tile and halves staged bytes.
//  - log2-space softmax: SCALE*log2e folded into Q; v_exp_f32 (native 2^x)
//    via __builtin_amdgcn_exp2f; defer threshold 8*log2e. Reductions stay
//    shfl_xor (v7-proven; identical-source permlane32_swap is the suspected
//    v6 inf culprit and remains banned for reductions).
//  - pairwise max/sum trees (depth ~6 vs 31 serial).
// Lesson encoded: 3-buffer/96KB variants force 1 block/CU and lose ~2x
// (v7/v8); LDS must stay <= 80KB for 2 resident blocks.

namespace {

constexpr int Bc = 8, Sc = 1024, Hc = 32, KVHc = 8, Dc = 128;
constexpr float SCALEc = 0.08838834764831845f;
constexpr float LOG2E = 1.44269504088896f;
constexpr int KVBLK = 64;
constexpr int KD = KVHc * Dc;      // 1024
constexpr int HD = Hc * Dc;        // 4096
constexpr int NT = 17;             // tiles per block (uniform via band pairing)
constexpr int IMG = KVBLK * Dc;    // 8192 bf16 = 16 KB per tile image

typedef __attribute__((ext_vector_type(8))) short bf16x8;
typedef __attribute__((ext_vector_type(16))) float f32x16;

__device__ __forceinline__ float exp2fast(float x) {
  return __builtin_amdgcn_exp2f(x);   // v_exp_f32: 2^x
}
__device__ __forceinline__ unsigned short f2bf(float f) {
  union { __hip_bfloat16 h; unsigned short u; } c;
  c.h = __float2bfloat16(f);
  return c.u;
}
__device__ __forceinline__ unsigned pack2(float a, float b) {
  return (unsigned)f2bf(a) | ((unsigned)f2bf(b) << 16);
}
// Distinct-source operands only (PV packing) -- v5-proven.
__device__ __forceinline__ void pl32swap(unsigned& a, unsigned& b) {
  asm volatile("v_permlane32_swap_b32 %0, %1" : "+v"(a), "+v"(b));
}

// ---------------- pre-pass: build swizzled bf16 tile images ----------------
__global__ __launch_bounds__(256) void preconv(
    const float* __restrict__ kg, const float* __restrict__ vg,
    unsigned short* __restrict__ wsK, unsigned short* __restrict__ wsV) {
  const int img = blockIdx.x;            // (b*8+kvh)*16 + t
  const int t = img & 15;
  const int kvh = (img >> 4) & 7;
  const int b = img >> 7;
  const int tid = threadIdx.x;
  const size_t row0 = (size_t)(b * Sc + t * 64);

  // K image: byte r*256 + y  <-  bf16(K[r][(y ^ ((r&15)<<4))/2])
  uint4* outK = (uint4*)(wsK + (size_t)img * IMG);
  const float* kp = kg + row0 * KD + kvh * Dc;
#pragma unroll
  for (int cc = 0; cc < 4; ++cc) {
    const int c = cc * 256 + tid;        // 16B chunk id, 0..1023
    const int r = c >> 4, yc = c & 15;
    const int d0 = ((yc * 16) ^ ((r & 15) << 4)) >> 1;
    const float* s = kp + (size_t)r * KD + d0;
    float4 x = *(const float4*)(s);
    float4 y = *(const float4*)(s + 4);
    uint4 o;
    o.x = pack2(x.x, x.y); o.y = pack2(x.z, x.w);
    o.z = pack2(y.x, y.y); o.w = pack2(y.z, y.w);
    outK[c] = o;
  }

  // V^T image via LDS bounce: byte d*128 + y <- bf16(V[(y^((d&7)<<4))/2][d])
  __shared__ unsigned short tmp[64 * 128];   // [key][d] bf16, linear
  const float* vp = vg + row0 * KD + kvh * Dc;
#pragma unroll
  for (int cc = 0; cc < 8; ++cc) {
    const int c2 = cc * 256 + tid;       // 0..2047, 4 floats each
    const int key = c2 >> 5, dc = (c2 & 31) * 4;
    float4 x = *(const float4*)(vp + (size_t)key * KD + dc);
    uint2 o;
    o.x = pack2(x.x, x.y); o.y = pack2(x.z, x.w);
    *(uint2*)(tmp + key * 128 + dc) = o;
  }
  __syncthreads();
  uint4* outV = (uint4*)(wsV + (size_t)img * IMG);
#pragma unroll
  for (int cc = 0; cc < 4; ++cc) {
    const int c = cc * 256 + tid;        // 0..1023
    const int d = c >> 3, yc = c & 7;
    const int k0 = ((yc * 16) ^ ((d & 7) << 4)) >> 1;
    uint4 o;
    o.x = tmp[(k0 + 0) * 128 + d] | ((unsigned)tmp[(k0 + 1) * 128 + d] << 16);
    o.y = tmp[(k0 + 2) * 128 + d] | ((unsigned)tmp[(k0 + 3) * 128 + d] << 16);
    o.z = tmp[(k0 + 4) * 128 + d] | ((unsigned)tmp[(k0 + 5) * 128 + d] << 16);
    o.w = tmp[(k0 + 6) * 128 + d] | ((unsigned)tmp[(k0 + 7) * 128 + d] << 16);
    outV[c] = o;
  }
}

// ---------------- MFMA helpers ----------------
// QK^T subtile ST (32 keys): S^T fragment; lane holds q=lane&31,
// k_local = (reg&3)+8*(reg>>2)+4*hi (+ST*32).
template <int ST>
__device__ __forceinline__ f32x16 qk_sub(const unsigned short* KB,
                                         const bf16x8* qf, int q32, int hi) {
  f32x16 a;
#pragma unroll
  for (int i = 0; i < 16; ++i) a[i] = 0.f;
  const int key = ST * 32 + q32;
  const char* kb = (const char*)KB + key * 256;
  const int sw = (key & 15) << 4;
#pragma unroll
  for (int ks = 0; ks < 8; ++ks) {
    bf16x8 kf = *(const bf16x8*)(kb + ((ks * 32 + hi * 16) ^ sw));
    a = __builtin_amdgcn_mfma_f32_32x32x16_bf16(kf, qf[ks], a, 0, 0, 0);
  }
  return a;
}

// PV subtile ST: pack exp'd P to bf16 A-frags (permlane32_swap, distinct
// sources) and accumulate acc[dt] += V^T[d][k] * P^T[k][q].
template <int ST>
__device__ __forceinline__ void pv_sub(const unsigned short* VB,
                                       const f32x16& p, f32x16* acc,
                                       int q32, int hi) {
  unsigned cp[8];
#pragma unroll
  for (int j = 0; j < 8; ++j) cp[j] = pack2(p[2 * j], p[2 * j + 1]);
  pl32swap(cp[0], cp[2]);
  pl32swap(cp[1], cp[3]);
  pl32swap(cp[4], cp[6]);
  pl32swap(cp[5], cp[7]);
  union { bf16x8 v; unsigned u[4]; } f0, f1;
  f0.u[0] = cp[0]; f0.u[1] = cp[1]; f0.u[2] = cp[2]; f0.u[3] = cp[3];
  f1.u[0] = cp[4]; f1.u[1] = cp[5]; f1.u[2] = cp[6]; f1.u[3] = cp[7];
#pragma unroll
  for (int ks2 = 0; ks2 < 2; ++ks2) {
    const bf16x8 pa = ks2 ? f1.v : f0.v;
#pragma unroll
    for (int dt = 0; dt < 4; ++dt) {
      const int d = dt * 32 + q32;
      const bf16x8 vf = *(const bf16x8*)(
          (const char*)VB + d * 128 +
          ((ST * 64 + ks2 * 32 + hi * 16) ^ ((d & 7) << 4)));
      acc[dt] = __builtin_amdgcn_mfma_f32_32x32x16_bf16(vf, pa, acc[dt], 0, 0, 0);
    }
  }
}

// ---------------- main kernel ----------------
__global__ __launch_bounds__(512, 2) void attn_fwd(
    const float* __restrict__ qg,
    const unsigned short* __restrict__ wsK,
    const unsigned short* __restrict__ wsV,
    float* __restrict__ out) {
  const int bid = blockIdx.x;
  const int j   = bid >> 6;            // pair index 0..7
  const int kvh = bid & 7;
  const int b   = (bid >> 3) & 7;
  const int nA  = 16 - j;              // tiles in band A (= band 15-j)
  const int bh  = b * 8 + kvh;

  const int tid = threadIdx.x;
  const int w = tid >> 6, l = tid & 63;
  const int q32 = l & 31, hi = l >> 5;
  const int h = kvh * 4 + (w >> 1);
  const int stdiag = w & 1;

  int qbase = (15 - j) * 64 + (w & 1) * 32;   // band A first

  __shared__ unsigned short Kl[2][IMG];   // 32 KB
  __shared__ unsigned short Vt[2][IMG];   // 32 KB

  bf16x8 qf[8];
  auto LOADQ = [&](int qb_) {
    const float* qp = qg + (size_t)(b * Sc + qb_ + q32) * HD + h * Dc;
    const float sc = SCALEc * LOG2E;     // log2-space softmax
#pragma unroll
    for (int ks = 0; ks < 8; ++ks) {
      const int d0 = ks * 16 + hi * 8;
      float4 x = *(const float4*)(qp + d0);
      float4 y = *(const float4*)(qp + d0 + 4);
      bf16x8 t;
      t[0] = (short)f2bf(x.x * sc); t[1] = (short)f2bf(x.y * sc);
      t[2] = (short)f2bf(x.z * sc); t[3] = (short)f2bf(x.w * sc);
      t[4] = (short)f2bf(y.x * sc); t[5] = (short)f2bf(y.y * sc);
      t[6] = (short)f2bf(y.z * sc); t[7] = (short)f2bf(y.w * sc);
      qf[ks] = t;
    }
  };
  LOADQ(qbase);

  f32x16 acc[4];
#pragma unroll
  for (int dt = 0; dt < 4; ++dt)
#pragma unroll
    for (int i = 0; i < 16; ++i) acc[dt][i] = 0.f;
  float m = -1e30f, lsum = 0.f;

  auto WRITEO = [&](int qb_) {
    const float rinv = 1.0f / lsum;
    float* ob = out + (size_t)(b * Sc + qb_ + q32) * HD + h * Dc;
#pragma unroll
    for (int dt = 0; dt < 4; ++dt)
#pragma unroll
      for (int g = 0; g < 4; ++g) {
        float4 o;
        o.x = acc[dt][g * 4 + 0] * rinv;
        o.y = acc[dt][g * 4 + 1] * rinv;
        o.z = acc[dt][g * 4 + 2] * rinv;
        o.w = acc[dt][g * 4 + 3] * rinv;
        *(float4*)(ob + dt * 32 + g * 8 + hi * 4) = o;
      }
  };

  // staging regs: 32B per array per thread (images are LDS-layout dumps)
  uint4 ki0, ki1, vi0, vi1;
  auto LOAD = [&](int T) {
    const uint4* sK = (const uint4*)(wsK + ((size_t)bh * 16 + T) * IMG);
    const uint4* sV = (const uint4*)(wsV + ((size_t)bh * 16 + T) * IMG);
    ki0 = sK[tid * 2]; ki1 = sK[tid * 2 + 1];
    vi0 = sV[tid * 2]; vi1 = sV[tid * 2 + 1];
  };
  auto STORE = [&](int cb) {
    uint4* dK = (uint4*)Kl[cb];
    uint4* dV = (uint4*)Vt[cb];
    dK[tid * 2] = ki0; dK[tid * 2 + 1] = ki1;
    dV[tid * 2] = vi0; dV[tid * 2 + 1] = vi1;
  };
  auto KT = [&](int i) { return i < nA ? i : i - nA; };

  // prologue
  LOAD(0);
  STORE(0);
  LOAD(KT(1));
  __syncthreads();

  for (int i = 0; i < NT; ++i) {
    const int cb = i & 1;
    if (i + 1 < NT) {
      STORE(cb ^ 1);                     // regs(i+1) -> other buffer
      if (i + 2 < NT) LOAD(KT(i + 2));   // prefetch depth 2
    }
    if (i == nA) {                       // band switch
      WRITEO(qbase);
      qbase = j * 64 + (w & 1) * 32;
      LOADQ(qbase);
#pragma unroll
      for (int dt = 0; dt < 4; ++dt)
#pragma unroll
        for (int z = 0; z < 16; ++z) acc[dt][z] = 0.f;
      m = -1e30f;
      lsum = 0.f;
    }
    const int kt = KT(i);
    const unsigned short* KB = Kl[cb];
    const unsigned short* VB = Vt[cb];
    const bool last = (i == nA - 1) || (i == NT - 1);
    const bool has1 = !(last && stdiag == 0);

    // ---- QK^T (swapped; scores in log2 units) ----
    f32x16 p0, p1;
    __builtin_amdgcn_s_setprio(1);
    p0 = qk_sub<0>(KB, qf, q32, hi);
    if (has1) {
      p1 = qk_sub<1>(KB, qf, q32, hi);
    } else {
#pragma unroll
      for (int z = 0; z < 16; ++z) p1[z] = -1e30f;
    }
    __builtin_amdgcn_s_setprio(0);

    // ---- causal mask on diagonal subtile of last tile of each band ----
    if (last) {
      const int kmb = kt * KVBLK + stdiag * 32 + 4 * hi - qbase - q32;
      if (stdiag == 0) {
#pragma unroll
        for (int z = 0; z < 16; ++z) {
          const int kl = (z & 3) + 8 * (z >> 2);
          if (kmb + kl > 0) p0[z] = -1e30f;
        }
      } else {
#pragma unroll
        for (int z = 0; z < 16; ++z) {
          const int kl = (z & 3) + 8 * (z >> 2);
          if (kmb + kl > 0) p1[z] = -1e30f;
        }
      }
    }

    // ---- online softmax (log2 space), pairwise trees ----
    float t8[8];
#pragma unroll
    for (int z = 0; z < 8; ++z) t8[z] = fmaxf(p0[2 * z], p0[2 * z + 1]);
    if (has1) {
#pragma unroll
      for (int z = 0; z < 8; ++z)
        t8[z] = fmaxf(t8[z], fmaxf(p1[2 * z], p1[2 * z + 1]));
    }
    float pm = fmaxf(fmaxf(fmaxf(t8[0], t8[1]), fmaxf(t8[2], t8[3])),
                     fmaxf(fmaxf(t8[4], t8[5]), fmaxf(t8[6], t8[7])));
    pm = fmaxf(pm, __shfl_xor(pm, 32));
    if (__any(pm > m + 11.5416f)) {      // defer-max, 8/ln2 in log2 units
      const float mn = fmaxf(m, pm);
      const float alpha = exp2fast(m - mn);
      m = mn;
      lsum *= alpha;
#pragma unroll
      for (int dt = 0; dt < 4; ++dt) acc[dt] *= alpha;
    }
    float s8[8];
#pragma unroll
    for (int z = 0; z < 16; ++z) p0[z] = exp2fast(p0[z] - m);
#pragma unroll
    for (int z = 0; z < 8; ++z) s8[z] = p0[2 * z] + p0[2 * z + 1];
    if (has1) {
#pragma unroll
      for (int z = 0; z < 16; ++z) p1[z] = exp2fast(p1[z] - m);
#pragma unroll
      for (int z = 0; z < 8; ++z) s8[z] += p1[2 * z] + p1[2 * z + 1];
    }
    float se = ((s8[0] + s8[1]) + (s8[2] + s8[3])) +
               ((s8[4] + s8[5]) + (s8[6] + s8[7]));
    se += __shfl_xor(se, 32);
    lsum += se;

    // ---- PV ----
    __builtin_amdgcn_s_setprio(1);
    pv_sub<0>(VB, p0, acc, q32, hi);
    if (has1) pv_sub<1>(VB, p1, acc, q32, hi);
    __builtin_amdgcn_s_setprio(0);

    __syncthreads();
  }

  WRITEO(qbase);
}

// ---------------- fallback (no ws): proven v5 kernel ----------------
__global__ __launch_bounds__(512, 2) void attn_fwd_fb(
    const float* __restrict__ qg, const float* __restrict__ kg,
    const float* __restrict__ vg, float* __restrict__ out) {
  const int bid = blockIdx.x;
  const int j   = bid >> 6;
  const int kvh = bid & 7;
  const int b   = (bid >> 3) & 7;
  const int nA  = 16 - j;

  const int tid = threadIdx.x;
  const int w = tid >> 6, l = tid & 63;
  const int q32 = l & 31, hi = l >> 5;
  const int h = kvh * 4 + (w >> 1);
  const int stdiag = w & 1;

  int qbase = (15 - j) * 64 + (w & 1) * 32;

  __shared__ unsigned short Kl[2][KVBLK * Dc];
  __shared__ unsigned short Vt[2][Dc * KVBLK];

  bf16x8 qf[8];
  auto LOADQ = [&](int qb_) {
    const float* qp = qg + (size_t)(b * Sc + qb_ + q32) * HD + h * Dc;
#pragma unroll
    for (int ks = 0; ks < 8; ++ks) {
      const int d0 = ks * 16 + hi * 8;
      float4 x = *(const float4*)(qp + d0);
      float4 y = *(const float4*)(qp + d0 + 4);
      bf16x8 t;
      t[0] = (short)f2bf(x.x * SCALEc); t[1] = (short)f2bf(x.y * SCALEc);
      t[2] = (short)f2bf(x.z * SCALEc); t[3] = (short)f2bf(x.w * SCALEc);
      t[4] = (short)f2bf(y.x * SCALEc); t[5] = (short)f2bf(y.y * SCALEc);
      t[6] = (short)f2bf(y.z * SCALEc); t[7] = (short)f2bf(y.w * SCALEc);
      qf[ks] = t;
    }
  };
  LOADQ(qbase);

  f32x16 acc[4];
#pragma unroll
  for (int dt = 0; dt < 4; ++dt)
#pragma unroll
    for (int i = 0; i < 16; ++i) acc[dt][i] = 0.f;
  float m = -1e30f, lsum = 0.f;

  auto WRITEO = [&](int qb_) {
    const float rinv = 1.0f / lsum;
    float* ob = out + (size_t)(b * Sc + qb_ + q32) * HD + h * Dc;
#pragma unroll
    for (int dt = 0; dt < 4; ++dt)
#pragma unroll
      for (int g = 0; g < 4; ++g) {
        float4 o;
        o.x = acc[dt][g * 4 + 0] * rinv;
        o.y = acc[dt][g * 4 + 1] * rinv;
        o.z = acc[dt][g * 4 + 2] * rinv;
        o.w = acc[dt][g * 4 + 3] * rinv;
        *(float4*)(ob + dt * 32 + g * 8 + hi * 4) = o;
      }
  };

  const float* kb0 = kg + (size_t)(b * Sc) * KD + kvh * Dc;
  const float* vb0 = vg + (size_t)(b * Sc) * KD + kvh * Dc;
  const int krow = tid >> 3, kd0 = (tid & 7) * 16;
  const int vd = tid & 127, vk0 = (tid >> 7) * 16;
  float4 kreg[4];
  float vreg[16];

  auto LOAD = [&](int T) {
    const float* kp = kb0 + ((size_t)T * KVBLK + krow) * KD + kd0;
    kreg[0] = *(const float4*)(kp);
    kreg[1] = *(const float4*)(kp + 4);
    kreg[2] = *(const float4*)(kp + 8);
    kreg[3] = *(const float4*)(kp + 12);
    const float* vp = vb0 + ((size_t)T * KVBLK + vk0) * KD + vd;
#pragma unroll
    for (int jj = 0; jj < 16; ++jj) vreg[jj] = vp[(size_t)jj * KD];
  };
  auto STORE = [&](int cb) {
    unsigned short* KB = Kl[cb];
    unsigned short* VB = Vt[cb];
    uint4 A, Bq;
    A.x = pack2(kreg[0].x, kreg[0].y); A.y = pack2(kreg[0].z, kreg[0].w);
    A.z = pack2(kreg[1].x, kreg[1].y); A.w = pack2(kreg[1].z, kreg[1].w);
    Bq.x = pack2(kreg[2].x, kreg[2].y); Bq.y = pack2(kreg[2].z, kreg[2].w);
    Bq.z = pack2(kreg[3].x, kreg[3].y); Bq.w = pack2(kreg[3].z, kreg[3].w);
    const int kbase = krow * 256, ksw = (krow & 15) << 4;
    *(uint4*)((char*)KB + kbase + ((kd0 * 2) ^ ksw)) = A;
    *(uint4*)((char*)KB + kbase + ((kd0 * 2 + 16) ^ ksw)) = Bq;
    uint4 C0, C1;
    C0.x = pack2(vreg[0], vreg[1]);   C0.y = pack2(vreg[2], vreg[3]);
    C0.z = pack2(vreg[4], vreg[5]);   C0.w = pack2(vreg[6], vreg[7]);
    C1.x = pack2(vreg[8], vreg[9]);   C1.y = pack2(vreg[10], vreg[11]);
    C1.z = pack2(vreg[12], vreg[13]); C1.w = pack2(vreg[14], vreg[15]);
    const int vbase = vd * 128, vsw = (vd & 7) << 4;
    *(uint4*)((char*)VB + vbase + ((vk0 * 2) ^ vsw)) = C0;
    *(uint4*)((char*)VB + vbase + ((vk0 * 2 + 16) ^ vsw)) = C1;
  };
  auto KT = [&](int i) { return i < nA ? i : i - nA; };

  LOAD(0);
  STORE(0);
  LOAD(KT(1));
  __syncthreads();

  for (int i = 0; i < NT; ++i) {
    const int cb = i & 1;
    if (i + 1 < NT) {
      STORE(cb ^ 1);
      if (i + 2 < NT) LOAD(KT(i + 2));
    }
    if (i == nA) {
      WRITEO(qbase);
      qbase = j * 64 + (w & 1) * 32;
      LOADQ(qbase);
#pragma unroll
      for (int dt = 0; dt < 4; ++dt)
#pragma unroll
        for (int z = 0; z < 16; ++z) acc[dt][z] = 0.f;
      m = -1e30f;
      lsum = 0.f;
    }
    const int kt = KT(i);
    const unsigned short* KB = Kl[cb];
    const unsigned short* VB = Vt[cb];
    const bool last = (i == nA - 1) || (i == NT - 1);
    const bool has1 = !(last && stdiag == 0);

    f32x16 s[2];
    __builtin_amdgcn_s_setprio(1);
    s[0] = qk_sub<0>(KB, qf, q32, hi);
    if (has1) {
      s[1] = qk_sub<1>(KB, qf, q32, hi);
    } else {
#pragma unroll
      for (int z = 0; z < 16; ++z) s[1][z] = -1e30f;
    }
    __builtin_amdgcn_s_setprio(0);

    if (last) {
      const int kmb = kt * KVBLK + stdiag * 32 + 4 * hi - qbase - q32;
      if (stdiag == 0) {
#pragma unroll
        for (int z = 0; z < 16; ++z) {
          const int kl = (z & 3) + 8 * (z >> 2);
          if (kmb + kl > 0) s[0][z] = -1e30f;
        }
      } else {
#pragma unroll
        for (int z = 0; z < 16; ++z) {
          const int kl = (z & 3) + 8 * (z >> 2);
          if (kmb + kl > 0) s[1][z] = -1e30f;
        }
      }
    }

    float pm = fmaxf(s[0][0], s[1][0]);
#pragma unroll
    for (int z = 1; z < 16; ++z) pm = fmaxf(pm, fmaxf(s[0][z], s[1][z]));
    pm = fmaxf(pm, __shfl_xor(pm, 32));
    if (__any(pm > m + 8.0f)) {
      const float mn = fmaxf(m, pm);
      const float alpha = __expf(m - mn);
      m = mn;
      lsum *= alpha;
#pragma unroll
      for (int dt = 0; dt < 4; ++dt) acc[dt] *= alpha;
    }
    float se = 0.f;
#pragma unroll
    for (int z = 0; z < 16; ++z) { s[0][z] = __expf(s[0][z] - m); se += s[0][z]; }
    if (has1) {
#pragma unroll
      for (int z = 0; z < 16; ++z) { s[1][z] = __expf(s[1][z] - m); se += s[1][z]; }
    }
    se += __shfl_xor(se, 32);
    lsum += se;

    __builtin_amdgcn_s_setprio(1);
    pv_sub<0>(VB, s[0], acc, q32, hi);
    if (has1) pv_sub<1>(VB, s[1], acc, q32, hi);
    __builtin_amdgcn_s_setprio(0);

    __syncthreads();
  }

  WRITEO(qbase);
}

}  // namespace

extern "C" void kernel_launch(void* const* d_in, const int* in_sizes, int n_in,
                              void* d_out, int out_size, void* d_ws, size_t ws_size,
                              hipStream_t stream) {
  const float* q = (const float*)d_in[0];
  const float* k = (const float*)d_in[1];
  const float* v = (const float*)d_in[2];
  float* out = (float*)d_out;
  const size_t need = (size_t)2 * 1024 * IMG * sizeof(unsigned short);  // 32 MB
  if (ws_size >= need) {
    unsigned short* wsK = (unsigned short*)d_ws;
    unsigned short* wsV = wsK + (size_t)1024 * IMG;
    preconv<<<dim3(1024), dim3(256), 0, stream>>>(k, v, wsK, wsV);
    attn_fwd<<<dim3(512), dim3(512), 0, stream>>>(q, wsK, wsV, out);
  } else {
    attn_fwd_fb<<<dim3(512), dim3(512), 0, stream>>>(q, k, v, out);
  }
}